// Round 3
// baseline (182.320 us; speedup 1.0000x reference)
//
#include <hip/hip_runtime.h>
#include <math.h>

// Problem constants
#define H_GRID 32
#define W_GRID 64
#define NTOK   2048
#define NHEADS 8
#define HD     24
#define DIMC   192
#define BATCH  4

static constexpr float SCALE = 0.20412414523193154f; // 1/sqrt(24)

typedef unsigned short ushort;
typedef unsigned int   uint;
typedef __attribute__((ext_vector_type(8))) short bf16x8;
typedef __attribute__((ext_vector_type(4))) float f32x4;

static __device__ __forceinline__ float4 ld4(const float* p) { return *(const float4*)p; }

static __device__ __forceinline__ ushort f2bf(float f) {   // RNE to bf16
    union { float f; uint u; } c; c.f = f;
    uint u = c.u;
    uint r = u + 0x7fffu + ((u >> 16) & 1u);
    return (ushort)(r >> 16);
}
static __device__ __forceinline__ float bf2f(ushort h) {
    union { uint u; float f; } c; c.u = ((uint)h) << 16; return c.f;
}

// ---------------------------------------------------------------------------
// Fused cast: split x, qkv_w, proj_w into bf16 hi/lo pairs (float4-vectorized)
// ---------------------------------------------------------------------------
__global__ __launch_bounds__(256) void cast_all(const float* __restrict__ x,
                                                const float* __restrict__ wq,
                                                const float* __restrict__ wp,
                                                ushort* __restrict__ xhi, ushort* __restrict__ xlo,
                                                ushort* __restrict__ wqhi, ushort* __restrict__ wqlo,
                                                ushort* __restrict__ wphi, ushort* __restrict__ wplo) {
    const int i = blockIdx.x * 256 + threadIdx.x;   // float4 chunk index
    const float* src; ushort *dh, *dl; int off;
    if (i < 393216)      { src = x;  dh = xhi;  dl = xlo;  off = i; }
    else if (i < 420864) { src = wq; dh = wqhi; dl = wqlo; off = i - 393216; }
    else                 { src = wp; dh = wphi; dl = wplo; off = i - 420864; }
    float4 v = ld4(src + (size_t)off * 4);
    float a[4] = {v.x, v.y, v.z, v.w};
    ushort h[4], l[4];
#pragma unroll
    for (int j = 0; j < 4; j++) {
        h[j] = f2bf(a[j]);
        l[j] = f2bf(a[j] - bf2f(h[j]));
    }
    *(ushort4*)(dh + (size_t)off * 4) = make_ushort4(h[0], h[1], h[2], h[3]);
    *(ushort4*)(dl + (size_t)off * 4) = make_ushort4(l[0], l[1], l[2], l[3]);
}

// ---------------------------------------------------------------------------
// Split-bf16 MFMA GEMM: C[M x Nc] = A[M x 192] * W[Nc x 192]^T + bias
// A ~ Ahi+Alo, W ~ Whi+Wlo (bf16).  C ≈ Ahi*Whi + Alo*Whi + Ahi*Wlo.
// No LDS, no barriers: each lane's mfma fragment (8 consecutive k bf16 = 16B)
// is loaded straight from global (L1/L2-resident).
// Block = 4 waves; wave w computes rows [bx*64 + 16w, +16) x cols [by*64, +64).
// MODE 0: qkv scatter (q scaled); MODE 1: direct store.
// ---------------------------------------------------------------------------
template <int MODE>
__global__ __launch_bounds__(256) void gemm_mfma(const ushort* __restrict__ Ahi,
                                                 const ushort* __restrict__ Alo,
                                                 const ushort* __restrict__ Whi,
                                                 const ushort* __restrict__ Wlo,
                                                 const float* __restrict__ bias,
                                                 float* __restrict__ out,
                                                 float* __restrict__ qws,
                                                 float* __restrict__ kws,
                                                 float* __restrict__ vws) {
    const int t    = threadIdx.x;
    const int wave = t >> 6, lane = t & 63;
    const int m0   = blockIdx.x * 64 + wave * 16;
    const int j0   = blockIdx.y * 64;
    const int row  = lane & 15;     // A-row / B-col / C-col selector
    const int kq   = lane >> 4;     // 0..3 -> k offset 8*kq

    const ushort* ah = Ahi + (size_t)(m0 + row) * 192 + kq * 8;
    const ushort* al = Alo + (size_t)(m0 + row) * 192 + kq * 8;

    f32x4 acc[4] = {f32x4{0,0,0,0}, f32x4{0,0,0,0}, f32x4{0,0,0,0}, f32x4{0,0,0,0}};

#pragma unroll
    for (int ks = 0; ks < 6; ks++) {
        bf16x8 afh = *(const bf16x8*)(ah + ks * 32);
        bf16x8 afl = *(const bf16x8*)(al + ks * 32);
#pragma unroll
        for (int nt = 0; nt < 4; nt++) {
            const size_t boff = (size_t)(j0 + nt * 16 + row) * 192 + kq * 8 + ks * 32;
            bf16x8 bfh = *(const bf16x8*)(Whi + boff);
            bf16x8 bfl = *(const bf16x8*)(Wlo + boff);
            acc[nt] = __builtin_amdgcn_mfma_f32_16x16x32_bf16(afh, bfh, acc[nt], 0, 0, 0);
            acc[nt] = __builtin_amdgcn_mfma_f32_16x16x32_bf16(afl, bfh, acc[nt], 0, 0, 0);
            acc[nt] = __builtin_amdgcn_mfma_f32_16x16x32_bf16(afh, bfl, acc[nt], 0, 0, 0);
        }
    }

    // C/D layout: col = lane&15, row = (lane>>4)*4 + reg   [measured m89]
#pragma unroll
    for (int nt = 0; nt < 4; nt++) {
        const int col = j0 + nt * 16 + row;
        const float bv = bias[col];
#pragma unroll
        for (int r = 0; r < 4; r++) {
            const int m  = m0 + kq * 4 + r;
            float val = acc[nt][r] + bv;
            if (MODE == 0) {
                const int b_    = m >> 11;
                const int n     = m & 2047;
                const int which = col / 192;
                const int rr    = col - which * 192;
                const int head  = rr / 24;
                const int d     = rr - head * 24;
                const int dst   = ((b_ * 8 + head) * 2048 + n) * 24 + d;
                if (which == 0)      qws[dst] = val * SCALE;
                else if (which == 1) kws[dst] = val;
                else                 vws[dst] = val;
            } else {
                out[(size_t)m * 192 + col] = val;
            }
        }
    }
}

// ---------------------------------------------------------------------------
// Tiled local attention (unchanged from R2 except epilogue emits bf16 hi/lo).
// One block per (batch, head, 4x8 query tile); key superset <= 10x18 in LDS.
// ---------------------------------------------------------------------------
__global__ __launch_bounds__(256) void attn_tile(const float* __restrict__ q,
                                                 const float* __restrict__ k,
                                                 const float* __restrict__ v,
                                                 ushort* __restrict__ ahi,
                                                 ushort* __restrict__ alo) {
    const int qtile = blockIdx.x;
    const int head  = blockIdx.y;
    const int b     = blockIdx.z;
    const int qh0   = (qtile >> 3) * 4;
    const int qw0   = (qtile & 7) * 8;

    const int kh0 = max(qh0 - 3, 0), kh1 = min(qh0 + 6, H_GRID - 1);
    const int kw0 = max(qw0 - 5, 0), kw1 = min(qw0 + 12, W_GRID - 1);
    const int khc = kh1 - kh0 + 1;
    const int kwc = kw1 - kw0 + 1;
    const int nk  = khc * kwc;

    const int t = threadIdx.x;
    const float* kbase = &k[(size_t)((b * 8 + head) * 2048) * 24];
    const float* vbase = &v[(size_t)((b * 8 + head) * 2048) * 24];
    const float* qbase = &q[(size_t)((b * 8 + head) * 2048) * 24];

    __shared__ float KsT[24][192];
    __shared__ float Vs[180][28];
    __shared__ float qsT[24][32];
    __shared__ float Sc[32][196];
    __shared__ int   khw[192];
    __shared__ int   toks[192];
    __shared__ float rs[32];

    if (t < 192) {
        if (t < nk) {
            const int rr = t / kwc;
            const int cc = t - rr * kwc;
            const int kh = kh0 + rr, kw = kw0 + cc;
            khw[t]  = (kh << 8) | kw;
            toks[t] = (kh << 6) + kw;
        } else {
            khw[t] = 0x7F7F;
        }
        const int ql = t & 31, dq = t >> 5;
        const int tq = ((qh0 + (ql >> 3)) << 6) + qw0 + (ql & 7);
        float4 qv = ld4(&qbase[tq * 24 + dq * 4]);
        qsT[dq * 4 + 0][ql] = qv.x; qsT[dq * 4 + 1][ql] = qv.y;
        qsT[dq * 4 + 2][ql] = qv.z; qsT[dq * 4 + 3][ql] = qv.w;
    }
    __syncthreads();

    for (int i = t; i < 1152; i += 256) {
        const int slot = i % 192;
        const int dq   = i / 192;
        if (slot < nk) {
            const int tok = toks[slot];
            float4 kv = ld4(&kbase[tok * 24 + dq * 4]);
            KsT[dq * 4 + 0][slot] = kv.x; KsT[dq * 4 + 1][slot] = kv.y;
            KsT[dq * 4 + 2][slot] = kv.z; KsT[dq * 4 + 3][slot] = kv.w;
            float4 vv = ld4(&vbase[tok * 24 + dq * 4]);
            *(float4*)&Vs[slot][dq * 4] = vv;
        }
    }
    __syncthreads();

    {
        const int kq = t & 7;
        const int qg = (t >> 3) & 7;
        const int jw = t >> 6;
        for (int j = jw; j < 6; j += 4) {
            const int s0 = j * 32 + kq * 4;
            float acc[4][4] = {};
#pragma unroll
            for (int d = 0; d < 24; d++) {
                float4 q4 = *(const float4*)&qsT[d][qg * 4];
                float4 k4 = *(const float4*)&KsT[d][s0];
                float qa[4] = {q4.x, q4.y, q4.z, q4.w};
                float ka[4] = {k4.x, k4.y, k4.z, k4.w};
#pragma unroll
                for (int u = 0; u < 4; u++)
#pragma unroll
                    for (int w = 0; w < 4; w++) acc[u][w] += qa[u] * ka[w];
            }
            const int4 kh4 = *(const int4*)&khw[s0];
            const int khwv[4] = {kh4.x, kh4.y, kh4.z, kh4.w};
#pragma unroll
            for (int u = 0; u < 4; u++) {
                const int qq = qg * 4 + u;
                const int qh = qh0 + (qq >> 3);
                const int qw = qw0 + (qq & 7);
                float o[4];
#pragma unroll
                for (int w = 0; w < 4; w++) {
                    const int kh = khwv[w] >> 8, kw = khwv[w] & 255;
                    const bool valid = (abs(kh - qh) <= 3) && (abs(kw - qw) <= 5);
                    o[w] = valid ? acc[u][w] : -1e30f;
                }
                *(float4*)&Sc[qq][s0] = make_float4(o[0], o[1], o[2], o[3]);
            }
        }
    }
    __syncthreads();

    {
        const int ql = t >> 3, kg = t & 7;
        float vals[24];
        float m = -1e30f;
#pragma unroll
        for (int i = 0; i < 24; i++) {
            vals[i] = Sc[ql][kg + 8 * i];
            m = fmaxf(m, vals[i]);
        }
        m = fmaxf(m, __shfl_xor(m, 1));
        m = fmaxf(m, __shfl_xor(m, 2));
        m = fmaxf(m, __shfl_xor(m, 4));
        float s = 0.f;
#pragma unroll
        for (int i = 0; i < 24; i++) {
            float p = __expf(vals[i] - m);
            s += p;
            Sc[ql][kg + 8 * i] = p;
        }
        s += __shfl_xor(s, 1);
        s += __shfl_xor(s, 2);
        s += __shfl_xor(s, 4);
        if (kg == 0) rs[ql] = 1.0f / s;
    }
    __syncthreads();

    if (t < 192) {
        const int ql = t / 6, dq = t - (t / 6) * 6;
        const int qh = qh0 + (ql >> 3);
        const int qw = qw0 + (ql & 7);
        const int r0 = max(qh - 3, 0) - kh0, r1 = min(qh + 3, H_GRID - 1) - kh0;
        const int c0 = max(qw - 5, 0) - kw0, c1 = min(qw + 5, W_GRID - 1) - kw0;
        float4 o = make_float4(0.f, 0.f, 0.f, 0.f);
        for (int rr = r0; rr <= r1; rr++) {
            const int sbase = rr * kwc;
            for (int cc = c0; cc <= c1; cc++) {
                const float p = Sc[ql][sbase + cc];
                const float4 vv = *(const float4*)&Vs[sbase + cc][dq * 4];
                o.x += p * vv.x; o.y += p * vv.y; o.z += p * vv.z; o.w += p * vv.w;
            }
        }
        const float r = rs[ql];
        const int tq = ((qh0 + (ql >> 3)) << 6) + qw0 + (ql & 7);
        float vals[4] = {o.x * r, o.y * r, o.z * r, o.w * r};
        ushort h[4], l[4];
#pragma unroll
        for (int j = 0; j < 4; j++) {
            h[j] = f2bf(vals[j]);
            l[j] = f2bf(vals[j] - bf2f(h[j]));
        }
        const size_t ob = (size_t)(b * 2048 + tq) * 192 + head * 24 + dq * 4;
        *(ushort4*)&ahi[ob] = make_ushort4(h[0], h[1], h[2], h[3]);
        *(ushort4*)&alo[ob] = make_ushort4(l[0], l[1], l[2], l[3]);
    }
}

// ---------------------------------------------------------------------------
// Launch: cast -> qkv MFMA GEMM -> attention (emits bf16 hi/lo) -> proj GEMM
// ---------------------------------------------------------------------------
extern "C" void kernel_launch(void* const* d_in, const int* in_sizes, int n_in,
                              void* d_out, int out_size, void* d_ws, size_t ws_size,
                              hipStream_t stream) {
    const float* x      = (const float*)d_in[0];
    const float* qkv_w  = (const float*)d_in[1];
    const float* qkv_b  = (const float*)d_in[2];
    const float* proj_w = (const float*)d_in[3];
    const float* proj_b = (const float*)d_in[4];
    // d_in[5] mask: fixed 7x11 window, recomputed analytically; unused.

    char* wsb = (char*)d_ws;
    float*  qws   = (float*)(wsb + 0);          // [4,8,2048,24] f32
    float*  kws   = (float*)(wsb + 6291456);
    float*  vws   = (float*)(wsb + 12582912);
    ushort* awshi = (ushort*)(wsb + 18874368);  // [4,2048,192] bf16 hi
    ushort* awslo = (ushort*)(wsb + 22020096);  //              bf16 lo
    ushort* xhi   = (ushort*)(wsb + 25165824);  // [8192,192]
    ushort* xlo   = (ushort*)(wsb + 28311552);
    ushort* wqhi  = (ushort*)(wsb + 31457280);  // [576,192]
    ushort* wqlo  = (ushort*)(wsb + 31678464);
    ushort* wphi  = (ushort*)(wsb + 31899648);  // [192,192]
    ushort* wplo  = (ushort*)(wsb + 31973376);
    float*  out   = (float*)d_out;

    dim3 blk(256);

    hipLaunchKernelGGL(cast_all, dim3(1680), blk, 0, stream,
                       x, qkv_w, proj_w, xhi, xlo, wqhi, wqlo, wphi, wplo);
    hipLaunchKernelGGL((gemm_mfma<0>), dim3(128, 9), blk, 0, stream,
                       xhi, xlo, wqhi, wqlo, qkv_b, (float*)nullptr, qws, kws, vws);
    hipLaunchKernelGGL(attn_tile, dim3(64, 8, 4), blk, 0, stream,
                       qws, kws, vws, awshi, awslo);
    hipLaunchKernelGGL((gemm_mfma<1>), dim3(128, 3), blk, 0, stream,
                       awshi, awslo, wphi, wplo, proj_b, out,
                       (float*)nullptr, (float*)nullptr, (float*)nullptr);
}

// Round 4
// 151.598 us; speedup vs baseline: 1.2027x; 1.2027x over previous
//
#include <hip/hip_runtime.h>
#include <math.h>

// Problem constants
#define H_GRID 32
#define W_GRID 64
#define NTOK   2048
#define NHEADS 8
#define HD     24
#define DIMC   192
#define BATCH  4

static constexpr float SCALE = 0.20412414523193154f; // 1/sqrt(24)

typedef unsigned short ushort;
typedef unsigned int   uint;
typedef __attribute__((ext_vector_type(8))) short bf16x8;
typedef __attribute__((ext_vector_type(4))) float f32x4;

static __device__ __forceinline__ float4 ld4(const float* p) { return *(const float4*)p; }

static __device__ __forceinline__ ushort f2bf(float f) {   // RNE to bf16
    union { float f; uint u; } c; c.f = f;
    uint u = c.u;
    uint r = u + 0x7fffu + ((u >> 16) & 1u);
    return (ushort)(r >> 16);
}
static __device__ __forceinline__ float bf2f(ushort h) {
    union { uint u; float f; } c; c.u = ((uint)h) << 16; return c.f;
}

// ---------------------------------------------------------------------------
// Fused cast: split x, qkv_w, proj_w into bf16 hi/lo pairs (float4-vectorized)
// ---------------------------------------------------------------------------
__global__ __launch_bounds__(256) void cast_all(const float* __restrict__ x,
                                                const float* __restrict__ wq,
                                                const float* __restrict__ wp,
                                                ushort* __restrict__ xhi, ushort* __restrict__ xlo,
                                                ushort* __restrict__ wqhi, ushort* __restrict__ wqlo,
                                                ushort* __restrict__ wphi, ushort* __restrict__ wplo) {
    const int i = blockIdx.x * 256 + threadIdx.x;   // float4 chunk index
    const float* src; ushort *dh, *dl; int off;
    if (i < 393216)      { src = x;  dh = xhi;  dl = xlo;  off = i; }
    else if (i < 420864) { src = wq; dh = wqhi; dl = wqlo; off = i - 393216; }
    else                 { src = wp; dh = wphi; dl = wplo; off = i - 420864; }
    float4 v = ld4(src + (size_t)off * 4);
    float a[4] = {v.x, v.y, v.z, v.w};
    ushort h[4], l[4];
#pragma unroll
    for (int j = 0; j < 4; j++) {
        h[j] = f2bf(a[j]);
        l[j] = f2bf(a[j] - bf2f(h[j]));
    }
    *(ushort4*)(dh + (size_t)off * 4) = make_ushort4(h[0], h[1], h[2], h[3]);
    *(ushort4*)(dl + (size_t)off * 4) = make_ushort4(l[0], l[1], l[2], l[3]);
}

// ---------------------------------------------------------------------------
// Split-bf16 MFMA GEMM: C[M x NC] = A[M x 192] * W[NC x 192]^T + bias
// - W band (64 cols x 192, hi+lo) staged in LDS once per block (flat copy,
//   conflict-free broadcast reads).
// - A fragments per-lane direct from global (16B, K-contiguous).
// - Dense row-major fp32 C stores (no scatter).
// Block = 4 waves; wave w: rows [bx*64+16w, +16) x cols [by*64, +64).
// ---------------------------------------------------------------------------
template <int NC>
__global__ __launch_bounds__(256) void gemm_mfma(const ushort* __restrict__ Ahi,
                                                 const ushort* __restrict__ Alo,
                                                 const ushort* __restrict__ Wh,
                                                 const ushort* __restrict__ Wl,
                                                 const float* __restrict__ bias,
                                                 float* __restrict__ C) {
    __shared__ ushort Wsh[64 * 192];
    __shared__ ushort Wsl[64 * 192];

    const int t    = threadIdx.x;
    const int wave = t >> 6, lane = t & 63;
    const int m0   = blockIdx.x * 64 + wave * 16;
    const int j0   = blockIdx.y * 64;
    const int row  = lane & 15;
    const int kq   = lane >> 4;

    // Stage W band: rows j0..j0+63 are contiguous (64*192 ushorts per array)
    {
        const uint4* gh = (const uint4*)(Wh + (size_t)j0 * 192);
        const uint4* gl = (const uint4*)(Wl + (size_t)j0 * 192);
        uint4* sh = (uint4*)Wsh;
        uint4* sl = (uint4*)Wsl;
#pragma unroll
        for (int i = 0; i < 6; i++) {
            sh[t + i * 256] = gh[t + i * 256];
            sl[t + i * 256] = gl[t + i * 256];
        }
    }

    const ushort* ah = Ahi + (size_t)(m0 + row) * 192 + kq * 8;
    const ushort* al = Alo + (size_t)(m0 + row) * 192 + kq * 8;

    f32x4 acc[4] = {f32x4{0,0,0,0}, f32x4{0,0,0,0}, f32x4{0,0,0,0}, f32x4{0,0,0,0}};

    __syncthreads();

#pragma unroll
    for (int ks = 0; ks < 6; ks++) {
        bf16x8 afh = *(const bf16x8*)(ah + ks * 32);
        bf16x8 afl = *(const bf16x8*)(al + ks * 32);
#pragma unroll
        for (int nt = 0; nt < 4; nt++) {
            const int widx = (nt * 16 + row) * 192 + kq * 8 + ks * 32;
            bf16x8 bh = *(const bf16x8*)&Wsh[widx];
            bf16x8 bl = *(const bf16x8*)&Wsl[widx];
            acc[nt] = __builtin_amdgcn_mfma_f32_16x16x32_bf16(afh, bh, acc[nt], 0, 0, 0);
            acc[nt] = __builtin_amdgcn_mfma_f32_16x16x32_bf16(afl, bh, acc[nt], 0, 0, 0);
            acc[nt] = __builtin_amdgcn_mfma_f32_16x16x32_bf16(afh, bl, acc[nt], 0, 0, 0);
        }
    }

    // C/D layout: col = lane&15 (+nt*16), row = kq*4 + reg  [verified R3 pass]
#pragma unroll
    for (int nt = 0; nt < 4; nt++) {
        const int col = j0 + nt * 16 + row;
        const float bv = bias[col];
#pragma unroll
        for (int r = 0; r < 4; r++) {
            const int m = m0 + kq * 4 + r;
            C[(size_t)m * NC + col] = acc[nt][r] + bv;
        }
    }
}

// ---------------------------------------------------------------------------
// Tiled local attention. One block per (batch, head, 4x8 query tile).
// Reads q/k/v from fused qkv [B*N, 576] layout (q scaled on load).
// Vs rows XOR-swizzled (stride 32, group dq ^ (slot&7)) -> conflict-free PV.
// Epilogue emits bf16 hi/lo for the proj GEMM.
// ---------------------------------------------------------------------------
__global__ __launch_bounds__(256) void attn_tile(const float* __restrict__ qkv,
                                                 ushort* __restrict__ ahi,
                                                 ushort* __restrict__ alo) {
    const int qtile = blockIdx.x;
    const int head  = blockIdx.y;
    const int b     = blockIdx.z;
    const int qh0   = (qtile >> 3) * 4;
    const int qw0   = (qtile & 7) * 8;

    const int kh0 = max(qh0 - 3, 0), kh1 = min(qh0 + 6, H_GRID - 1);
    const int kw0 = max(qw0 - 5, 0), kw1 = min(qw0 + 12, W_GRID - 1);
    const int khc = kh1 - kh0 + 1;
    const int kwc = kw1 - kw0 + 1;
    const int nk  = khc * kwc;

    const int t = threadIdx.x;
    const float* base = qkv + (size_t)b * 2048 * 576 + head * 24;

    __shared__ float KsT[24][192];
    __shared__ float Vs[180][32];    // XOR-swizzled float4 groups
    __shared__ float qsT[24][32];
    __shared__ float Sc[32][196];
    __shared__ int   khw[192];
    __shared__ int   toks[192];
    __shared__ float rs[32];

    if (t < 192) {
        if (t < nk) {
            const int rr = t / kwc;
            const int cc = t - rr * kwc;
            const int kh = kh0 + rr, kw = kw0 + cc;
            khw[t]  = (kh << 8) | kw;
            toks[t] = (kh << 6) + kw;
        } else {
            khw[t] = 0x7F7F;
        }
        const int ql = t & 31, dq = t >> 5;
        const int tq = ((qh0 + (ql >> 3)) << 6) + qw0 + (ql & 7);
        float4 qv = ld4(base + (size_t)tq * 576 + dq * 4);
        qsT[dq * 4 + 0][ql] = qv.x * SCALE; qsT[dq * 4 + 1][ql] = qv.y * SCALE;
        qsT[dq * 4 + 2][ql] = qv.z * SCALE; qsT[dq * 4 + 3][ql] = qv.w * SCALE;
    }
    __syncthreads();

    for (int i = t; i < 1152; i += 256) {        // 192 slots x 6 d-quads
        const int slot = i % 192;
        const int dq   = i / 192;
        if (slot < nk) {
            const int tok = toks[slot];
            float4 kv = ld4(base + (size_t)tok * 576 + 192 + dq * 4);
            KsT[dq * 4 + 0][slot] = kv.x; KsT[dq * 4 + 1][slot] = kv.y;
            KsT[dq * 4 + 2][slot] = kv.z; KsT[dq * 4 + 3][slot] = kv.w;
            float4 vv = ld4(base + (size_t)tok * 576 + 384 + dq * 4);
            *(float4*)&Vs[slot][(dq ^ (slot & 7)) * 4] = vv;
        }
    }
    __syncthreads();

    {
        const int kq = t & 7;
        const int qg = (t >> 3) & 7;
        const int jw = t >> 6;
        for (int j = jw; j < 6; j += 4) {
            const int s0 = j * 32 + kq * 4;
            float acc[4][4] = {};
#pragma unroll
            for (int d = 0; d < 24; d++) {
                float4 q4 = *(const float4*)&qsT[d][qg * 4];
                float4 k4 = *(const float4*)&KsT[d][s0];
                float qa[4] = {q4.x, q4.y, q4.z, q4.w};
                float ka[4] = {k4.x, k4.y, k4.z, k4.w};
#pragma unroll
                for (int u = 0; u < 4; u++)
#pragma unroll
                    for (int w = 0; w < 4; w++) acc[u][w] += qa[u] * ka[w];
            }
            const int4 kh4 = *(const int4*)&khw[s0];
            const int khwv[4] = {kh4.x, kh4.y, kh4.z, kh4.w};
#pragma unroll
            for (int u = 0; u < 4; u++) {
                const int qq = qg * 4 + u;
                const int qh = qh0 + (qq >> 3);
                const int qw = qw0 + (qq & 7);
                float o[4];
#pragma unroll
                for (int w = 0; w < 4; w++) {
                    const int kh = khwv[w] >> 8, kw = khwv[w] & 255;
                    const bool valid = (abs(kh - qh) <= 3) && (abs(kw - qw) <= 5);
                    o[w] = valid ? acc[u][w] : -1e30f;
                }
                *(float4*)&Sc[qq][s0] = make_float4(o[0], o[1], o[2], o[3]);
            }
        }
    }
    __syncthreads();

    {
        const int ql = t >> 3, kg = t & 7;
        float vals[24];
        float m = -1e30f;
#pragma unroll
        for (int i = 0; i < 24; i++) {
            vals[i] = Sc[ql][kg + 8 * i];
            m = fmaxf(m, vals[i]);
        }
        m = fmaxf(m, __shfl_xor(m, 1));
        m = fmaxf(m, __shfl_xor(m, 2));
        m = fmaxf(m, __shfl_xor(m, 4));
        float s = 0.f;
#pragma unroll
        for (int i = 0; i < 24; i++) {
            float p = __expf(vals[i] - m);
            s += p;
            Sc[ql][kg + 8 * i] = p;
        }
        s += __shfl_xor(s, 1);
        s += __shfl_xor(s, 2);
        s += __shfl_xor(s, 4);
        if (kg == 0) rs[ql] = 1.0f / s;
    }
    __syncthreads();

    if (t < 192) {
        const int ql = t / 6, dq = t - (t / 6) * 6;
        const int qh = qh0 + (ql >> 3);
        const int qw = qw0 + (ql & 7);
        const int r0 = max(qh - 3, 0) - kh0, r1 = min(qh + 3, H_GRID - 1) - kh0;
        const int c0 = max(qw - 5, 0) - kw0, c1 = min(qw + 5, W_GRID - 1) - kw0;
        float4 o = make_float4(0.f, 0.f, 0.f, 0.f);
        for (int rr = r0; rr <= r1; rr++) {
            const int sbase = rr * kwc;
            for (int cc = c0; cc <= c1; cc++) {
                const int slot = sbase + cc;
                const float p = Sc[ql][slot];
                const float4 vv = *(const float4*)&Vs[slot][(dq ^ (slot & 7)) * 4];
                o.x += p * vv.x; o.y += p * vv.y; o.z += p * vv.z; o.w += p * vv.w;
            }
        }
        const float r = rs[ql];
        const int tq = ((qh0 + (ql >> 3)) << 6) + qw0 + (ql & 7);
        float vals[4] = {o.x * r, o.y * r, o.z * r, o.w * r};
        ushort h[4], l[4];
#pragma unroll
        for (int j = 0; j < 4; j++) {
            h[j] = f2bf(vals[j]);
            l[j] = f2bf(vals[j] - bf2f(h[j]));
        }
        const size_t ob = (size_t)(b * 2048 + tq) * 192 + head * 24 + dq * 4;
        *(ushort4*)&ahi[ob] = make_ushort4(h[0], h[1], h[2], h[3]);
        *(ushort4*)&alo[ob] = make_ushort4(l[0], l[1], l[2], l[3]);
    }
}

// ---------------------------------------------------------------------------
// Launch: cast -> qkv GEMM (dense [8192,576]) -> attention -> proj GEMM
// ---------------------------------------------------------------------------
extern "C" void kernel_launch(void* const* d_in, const int* in_sizes, int n_in,
                              void* d_out, int out_size, void* d_ws, size_t ws_size,
                              hipStream_t stream) {
    const float* x      = (const float*)d_in[0];
    const float* qkv_b  = (const float*)d_in[2];
    const float* proj_b = (const float*)d_in[4];
    // d_in[5] mask: fixed 7x11 window, recomputed analytically; unused.

    char* wsb = (char*)d_ws;
    float*  qkvws = (float*)(wsb + 0);          // [8192,576] f32
    ushort* awshi = (ushort*)(wsb + 18874368);  // [8192,192] bf16 hi
    ushort* awslo = (ushort*)(wsb + 22020096);
    ushort* xhi   = (ushort*)(wsb + 25165824);  // [8192,192]
    ushort* xlo   = (ushort*)(wsb + 28311552);
    ushort* wqhi  = (ushort*)(wsb + 31457280);  // [576,192]
    ushort* wqlo  = (ushort*)(wsb + 31678464);
    ushort* wphi  = (ushort*)(wsb + 31899648);  // [192,192]
    ushort* wplo  = (ushort*)(wsb + 31973376);
    float*  out   = (float*)d_out;

    dim3 blk(256);

    hipLaunchKernelGGL(cast_all, dim3(1680), blk, 0, stream,
                       x, (const float*)d_in[1], (const float*)d_in[3],
                       xhi, xlo, wqhi, wqlo, wphi, wplo);
    hipLaunchKernelGGL((gemm_mfma<576>), dim3(128, 9), blk, 0, stream,
                       xhi, xlo, wqhi, wqlo, qkv_b, qkvws);
    hipLaunchKernelGGL(attn_tile, dim3(64, 8, 4), blk, 0, stream,
                       qkvws, awshi, awslo);
    hipLaunchKernelGGL((gemm_mfma<192>), dim3(128, 3), blk, 0, stream,
                       awshi, awslo, wphi, wplo, proj_b, out);
}

// Round 6
// 134.928 us; speedup vs baseline: 1.3512x; 1.1235x over previous
//
#include <hip/hip_runtime.h>
#include <math.h>

// Problem constants
#define H_GRID 32
#define W_GRID 64
#define NTOK   2048
#define NHEADS 8
#define HD     24
#define DIMC   192
#define BATCH  4

static constexpr float SCALE = 0.20412414523193154f; // 1/sqrt(24)

typedef unsigned short ushort;
typedef unsigned int   uint;
typedef __attribute__((ext_vector_type(8))) short bf16x8;
typedef __attribute__((ext_vector_type(4))) float f32x4;

static __device__ __forceinline__ float4 ld4(const float* p) { return *(const float4*)p; }

static __device__ __forceinline__ ushort f2bf(float f) {   // RNE to bf16
    union { float f; uint u; } c; c.f = f;
    uint u = c.u;
    uint r = u + 0x7fffu + ((u >> 16) & 1u);
    return (ushort)(r >> 16);
}
static __device__ __forceinline__ float bf2f(ushort h) {
    union { uint u; float f; } c; c.u = ((uint)h) << 16; return c.f;
}

// ---------------------------------------------------------------------------
// Weight cast only: split qkv_w and proj_w into bf16 hi/lo.
// 36864 float4 chunks: 27648 for wq, 9216 for wp.
// ---------------------------------------------------------------------------
__global__ __launch_bounds__(256) void cast_w(const float* __restrict__ wq,
                                              const float* __restrict__ wp,
                                              ushort* __restrict__ wqhi, ushort* __restrict__ wqlo,
                                              ushort* __restrict__ wphi, ushort* __restrict__ wplo) {
    const int i = blockIdx.x * 256 + threadIdx.x;
    const float* src; ushort *dh, *dl; int off;
    if (i < 27648) { src = wq; dh = wqhi; dl = wqlo; off = i; }
    else           { src = wp; dh = wphi; dl = wplo; off = i - 27648; }
    float4 v = ld4(src + (size_t)off * 4);
    float a[4] = {v.x, v.y, v.z, v.w};
    ushort h[4], l[4];
#pragma unroll
    for (int j = 0; j < 4; j++) {
        h[j] = f2bf(a[j]);
        l[j] = f2bf(a[j] - bf2f(h[j]));
    }
    *(ushort4*)(dh + (size_t)off * 4) = make_ushort4(h[0], h[1], h[2], h[3]);
    *(ushort4*)(dl + (size_t)off * 4) = make_ushort4(l[0], l[1], l[2], l[3]);
}

// ---------------------------------------------------------------------------
// QKV GEMM: C[8192 x 576] = x[8192 x 192] * W[576 x 192]^T + bias (split-bf16)
// - A (x) read fp32, split to bf16 hi/lo in-register (no cast round-trip).
// - W band in LDS, rows padded to 200 ushorts (100 words == 4 mod 32) ->
//   B-frag b128 reads 2-way (free); 192-stride was 16-way conflicted.
// - FIXED R5 BUG: stage loop now copies all 24 uint4 chunks/row (was 12).
// ---------------------------------------------------------------------------
__global__ __launch_bounds__(256) void gemm_qkv(const float* __restrict__ A,
                                                const ushort* __restrict__ Wh,
                                                const ushort* __restrict__ Wl,
                                                const float* __restrict__ bias,
                                                float* __restrict__ C) {
    __shared__ ushort Wsh[64 * 200];
    __shared__ ushort Wsl[64 * 200];

    const int t    = threadIdx.x;
    const int wave = t >> 6, lane = t & 63;
    const int m0   = blockIdx.x * 64 + wave * 16;
    const int j0   = blockIdx.y * 64;
    const int row  = lane & 15;
    const int kq   = lane >> 4;

    // Stage W band: 64 rows x 24 uint4 chunks = 1536 chunks (hi+lo)
    for (int i = t; i < 1536; i += 256) {
        const int r = i / 24, c = i - (i / 24) * 24;
        *(uint4*)&Wsh[r * 200 + c * 8] = *(const uint4*)&Wh[(size_t)(j0 + r) * 192 + c * 8];
        *(uint4*)&Wsl[r * 200 + c * 8] = *(const uint4*)&Wl[(size_t)(j0 + r) * 192 + c * 8];
    }

    const float* pA = A + (size_t)(m0 + row) * 192 + kq * 8;

    f32x4 acc[4] = {f32x4{0,0,0,0}, f32x4{0,0,0,0}, f32x4{0,0,0,0}, f32x4{0,0,0,0}};

    __syncthreads();

#pragma unroll
    for (int ks = 0; ks < 6; ks++) {
        float4 a0 = ld4(pA + ks * 32);
        float4 a1 = ld4(pA + ks * 32 + 4);
        float av[8] = {a0.x, a0.y, a0.z, a0.w, a1.x, a1.y, a1.z, a1.w};
        bf16x8 afh, afl;
#pragma unroll
        for (int j = 0; j < 8; j++) {
            ushort hh = f2bf(av[j]);
            afh[j] = (short)hh;
            afl[j] = (short)f2bf(av[j] - bf2f(hh));
        }
#pragma unroll
        for (int nt = 0; nt < 4; nt++) {
            const int widx = (nt * 16 + row) * 200 + kq * 8 + ks * 32;
            bf16x8 bh = *(const bf16x8*)&Wsh[widx];
            bf16x8 bl = *(const bf16x8*)&Wsl[widx];
            acc[nt] = __builtin_amdgcn_mfma_f32_16x16x32_bf16(afh, bh, acc[nt], 0, 0, 0);
            acc[nt] = __builtin_amdgcn_mfma_f32_16x16x32_bf16(afl, bh, acc[nt], 0, 0, 0);
            acc[nt] = __builtin_amdgcn_mfma_f32_16x16x32_bf16(afh, bl, acc[nt], 0, 0, 0);
        }
    }

    // C/D: col = lane&15 (+16nt), row = kq*4 + reg
#pragma unroll
    for (int nt = 0; nt < 4; nt++) {
        const int col = j0 + nt * 16 + row;
        const float bv = bias[col];
#pragma unroll
        for (int r = 0; r < 4; r++) {
            const int m = m0 + kq * 4 + r;
            C[(size_t)m * 576 + col] = acc[nt][r] + bv;
        }
    }
}

// ---------------------------------------------------------------------------
// MFMA local attention. One block (4 waves) per (b, head, 4x8 query tile).
// QK^T: 2 m-tiles x 12 n-tiles of 16x16x32 split-bf16 (K=24 padded to 32).
//   wave w: mt = w>>1, n-half = w&1 (6 n-tiles each). Scores stay in regs.
// Softmax: shuffle over 16 lanes + LDS exchange with partner wave.
// PV: P (split hi/lo bf16, rows padded to 232 us) as A-op, V^T as B-op;
//   K-dim = 192 slots = 6 ksteps; wave w -> C-tile (mt=w>>1, nt=w&1).
// P overlays the dead K region (barrier-separated). 66 KB LDS, 2 blocks/CU.
// ---------------------------------------------------------------------------
__global__ __launch_bounds__(256) void attn_mfma(const float* __restrict__ qkv,
                                                 ushort* __restrict__ ahi,
                                                 ushort* __restrict__ alo) {
    const int qtile = blockIdx.x;
    const int head  = blockIdx.y;
    const int b     = blockIdx.z;
    const int qh0   = (qtile >> 3) * 4;
    const int qw0   = (qtile & 7) * 8;

    const int kh0 = max(qh0 - 3, 0), kh1 = min(qh0 + 6, H_GRID - 1);
    const int kw0 = max(qw0 - 5, 0), kw1 = min(qw0 + 12, W_GRID - 1);
    const int khc = kh1 - kh0 + 1;
    const int kwc = kw1 - kw0 + 1;
    const int nk  = khc * kwc;          // <= 180 (n padded to 192)

    const int t = threadIdx.x;
    const int w = t >> 6, lane = t & 63;
    const int n16 = lane & 15, quad = lane >> 4;

    __shared__ __align__(16) char sm[67584];
    ushort* Khi   = (ushort*)(sm);            // [192][40]
    ushort* Klo   = (ushort*)(sm + 15360);
    ushort* Phi   = (ushort*)(sm);            // [32][232] overlays K (post-QK)
    ushort* Plo   = (ushort*)(sm + 14848);
    ushort* Qhi   = (ushort*)(sm + 30720);    // [32][40]
    ushort* Qlo   = (ushort*)(sm + 33280);
    ushort* VThi  = (ushort*)(sm + 35840);    // [32][232]  (d-major, slot contig)
    ushort* VTlo  = (ushort*)(sm + 50688);
    int*    khw   = (int*)(sm + 65536);       // [192] packed (kh<<8)|kw
    int*    toks  = (int*)(sm + 66304);       // [192]
    float*  mxbuf = (float*)(sm + 67072);     // [4][16]
    float*  sumbuf= (float*)(sm + 67328);     // [4][16]

    const float* base = qkv + (size_t)(b * 2048) * 576 + head * 24;

    // ---- geometry ----
    if (t < 192) {
        if (t < nk) {
            const int rr = t / kwc;
            const int cc = t - rr * kwc;
            khw[t]  = ((kh0 + rr) << 8) | (kw0 + cc);
            toks[t] = ((kh0 + rr) << 6) + (kw0 + cc);
        } else {
            khw[t] = 0x7F7F;                  // sentinel -> always masked
        }
    }
    __syncthreads();

    // ---- staging: K (row-major, k-octets), Q (same), V transposed ----
    for (int i = t; i < 768; i += 256) {       // K: 192 slots x 4 octets (g=3 pad)
        const int s = i >> 2, g = i & 3;
        ushort h[8], l[8];
        if (g < 3 && s < nk) {
            const float* src = base + (size_t)toks[s] * 576 + 192 + g * 8;
            float4 a = ld4(src), c = ld4(src + 4);
            float vs[8] = {a.x, a.y, a.z, a.w, c.x, c.y, c.z, c.w};
#pragma unroll
            for (int j = 0; j < 8; j++) { h[j] = f2bf(vs[j]); l[j] = f2bf(vs[j] - bf2f(h[j])); }
        } else {
#pragma unroll
            for (int j = 0; j < 8; j++) { h[j] = 0; l[j] = 0; }
        }
        *(uint4*)&Khi[s * 40 + g * 8] = *(uint4*)h;
        *(uint4*)&Klo[s * 40 + g * 8] = *(uint4*)l;
    }
    if (t < 128) {                             // Q: 32 rows x 4 octets (g=3 pad)
        const int r = t >> 2, g = t & 3;
        ushort h[8], l[8];
        if (g < 3) {
            const int tq = ((qh0 + (r >> 3)) << 6) + qw0 + (r & 7);
            const float* src = base + (size_t)tq * 576 + g * 8;
            float4 a = ld4(src), c = ld4(src + 4);
            float vs[8] = {a.x * SCALE, a.y * SCALE, a.z * SCALE, a.w * SCALE,
                           c.x * SCALE, c.y * SCALE, c.z * SCALE, c.w * SCALE};
#pragma unroll
            for (int j = 0; j < 8; j++) { h[j] = f2bf(vs[j]); l[j] = f2bf(vs[j] - bf2f(h[j])); }
        } else {
#pragma unroll
            for (int j = 0; j < 8; j++) { h[j] = 0; l[j] = 0; }
        }
        *(uint4*)&Qhi[r * 40 + g * 8] = *(uint4*)h;
        *(uint4*)&Qlo[r * 40 + g * 8] = *(uint4*)l;
    }
    for (int i = t; i < 1152; i += 256) {      // V -> VT[d][slot]
        const int dq = i / 192, s = i - (i / 192) * 192;
        float4 vv = make_float4(0.f, 0.f, 0.f, 0.f);
        if (s < nk) vv = ld4(base + (size_t)toks[s] * 576 + 384 + dq * 4);
        float vs[4] = {vv.x, vv.y, vv.z, vv.w};
#pragma unroll
        for (int c = 0; c < 4; c++) {
            const int d = dq * 4 + c;
            ushort hh = f2bf(vs[c]);
            VThi[d * 232 + s] = hh;
            VTlo[d * 232 + s] = f2bf(vs[c] - bf2f(hh));
        }
    }
    for (int j = t; j < 1536; j += 256) {      // VT pad rows 24..31 = 0
        const int d = 24 + j / 192, s = j - (j / 192) * 192;
        VThi[d * 232 + s] = 0;
        VTlo[d * 232 + s] = 0;
    }
    __syncthreads();

    // ---- QK^T: wave w -> mt = w>>1 (16 rows), n-half = w&1 (6 n-tiles) ----
    const int mt = w >> 1, nth = w & 1;
    const bf16x8 qfh = *(const bf16x8*)&Qhi[(16 * mt + n16) * 40 + quad * 8];
    const bf16x8 qfl = *(const bf16x8*)&Qlo[(16 * mt + n16) * 40 + quad * 8];

    f32x4 sc[6];
    int khwv[6];
#pragma unroll
    for (int j = 0; j < 6; j++) {
        const int slot = (nth * 6 + j) * 16 + n16;
        const bf16x8 kfh = *(const bf16x8*)&Khi[slot * 40 + quad * 8];
        const bf16x8 kfl = *(const bf16x8*)&Klo[slot * 40 + quad * 8];
        f32x4 a = f32x4{0, 0, 0, 0};
        a = __builtin_amdgcn_mfma_f32_16x16x32_bf16(qfh, kfh, a, 0, 0, 0);
        a = __builtin_amdgcn_mfma_f32_16x16x32_bf16(qfl, kfh, a, 0, 0, 0);
        a = __builtin_amdgcn_mfma_f32_16x16x32_bf16(qfh, kfl, a, 0, 0, 0);
        sc[j] = a;
        khwv[j] = khw[slot];
    }

    // ---- mask + row max ----
    const int m0r = quad * 4;
    float sv[6][4];
    float mx4[4] = {-1e30f, -1e30f, -1e30f, -1e30f};
#pragma unroll
    for (int j = 0; j < 6; j++) {
        const int kh = khwv[j] >> 8, kw = khwv[j] & 255;
#pragma unroll
        for (int r = 0; r < 4; r++) {
            const int m = 16 * mt + m0r + r;
            const bool valid = (abs(kh - (qh0 + (m >> 3))) <= 3) &&
                               (abs(kw - (qw0 + (m & 7))) <= 5);
            const float s = valid ? sc[j][r] : -1e30f;
            sv[j][r] = s;
            mx4[r] = fmaxf(mx4[r], s);
        }
    }
#pragma unroll
    for (int d = 1; d < 16; d <<= 1)
#pragma unroll
        for (int r = 0; r < 4; r++) mx4[r] = fmaxf(mx4[r], __shfl_xor(mx4[r], d));
    if (n16 == 0) {
#pragma unroll
        for (int r = 0; r < 4; r++) mxbuf[w * 16 + m0r + r] = mx4[r];
    }
    __syncthreads();
#pragma unroll
    for (int r = 0; r < 4; r++) mx4[r] = fmaxf(mx4[r], mxbuf[(w ^ 1) * 16 + m0r + r]);

    // ---- exp, P write (unnormalized, split bf16), partial row sums ----
    float sum4[4] = {0.f, 0.f, 0.f, 0.f};
#pragma unroll
    for (int j = 0; j < 6; j++) {
        const int col = (nth * 6 + j) * 16 + n16;
#pragma unroll
        for (int r = 0; r < 4; r++) {
            const float p = __expf(sv[j][r] - mx4[r]);
            sum4[r] += p;
            const int m = 16 * mt + m0r + r;
            const ushort ph = f2bf(p);
            Phi[m * 232 + col] = ph;
            Plo[m * 232 + col] = f2bf(p - bf2f(ph));
        }
    }
#pragma unroll
    for (int d = 1; d < 16; d <<= 1)
#pragma unroll
        for (int r = 0; r < 4; r++) sum4[r] += __shfl_xor(sum4[r], d);
    if (n16 == 0) {
#pragma unroll
        for (int r = 0; r < 4; r++) sumbuf[w * 16 + m0r + r] = sum4[r];
    }
    __syncthreads();

    // ---- PV: wave w -> C-tile (mtP = w>>1, ntP = w&1), K-dim 192 ----
    const int mtP = w >> 1, ntP = w & 1;
    f32x4 accA = f32x4{0,0,0,0}, accB = f32x4{0,0,0,0}, accC = f32x4{0,0,0,0};
#pragma unroll
    for (int ks = 0; ks < 6; ks++) {
        const int ko = ks * 32 + quad * 8;
        const bf16x8 pa = *(const bf16x8*)&Phi[(16 * mtP + n16) * 232 + ko];
        const bf16x8 pl = *(const bf16x8*)&Plo[(16 * mtP + n16) * 232 + ko];
        const bf16x8 va = *(const bf16x8*)&VThi[(16 * ntP + n16) * 232 + ko];
        const bf16x8 vl = *(const bf16x8*)&VTlo[(16 * ntP + n16) * 232 + ko];
        accA = __builtin_amdgcn_mfma_f32_16x16x32_bf16(pa, va, accA, 0, 0, 0);
        accB = __builtin_amdgcn_mfma_f32_16x16x32_bf16(pl, va, accB, 0, 0, 0);
        accC = __builtin_amdgcn_mfma_f32_16x16x32_bf16(pa, vl, accC, 0, 0, 0);
    }

    // ---- epilogue: normalize by row sum, emit bf16 hi/lo ----
    const int d = 16 * ntP + n16;
    if (d < 24) {
#pragma unroll
        for (int r = 0; r < 4; r++) {
            const int m   = 16 * mtP + quad * 4 + r;
            const float tot = sumbuf[(2 * mtP) * 16 + (m & 15)] +
                              sumbuf[(2 * mtP + 1) * 16 + (m & 15)];
            const float val = (accA[r] + accB[r] + accC[r]) / tot;
            const int tq = ((qh0 + (m >> 3)) << 6) + qw0 + (m & 7);
            const size_t ob = (size_t)(b * 2048 + tq) * 192 + head * 24 + d;
            const ushort hh = f2bf(val);
            ahi[ob] = hh;
            alo[ob] = f2bf(val - bf2f(hh));
        }
    }
}

// ---------------------------------------------------------------------------
// Proj GEMM: out[8192 x 192] = aws[8192 x 192] * W[192 x 192]^T + bias
// A pre-split bf16. 128-thread blocks, 32 rows -> 768 blocks.
// FIXED R5 BUG: stage loop copies all 1536 chunks (was 768).
// ---------------------------------------------------------------------------
__global__ __launch_bounds__(128) void gemm_proj(const ushort* __restrict__ Ahi,
                                                 const ushort* __restrict__ Alo,
                                                 const ushort* __restrict__ Wh,
                                                 const ushort* __restrict__ Wl,
                                                 const float* __restrict__ bias,
                                                 float* __restrict__ C) {
    __shared__ ushort Wsh[64 * 200];
    __shared__ ushort Wsl[64 * 200];

    const int t    = threadIdx.x;
    const int wave = t >> 6, lane = t & 63;
    const int m0   = blockIdx.x * 32 + wave * 16;
    const int j0   = blockIdx.y * 64;
    const int row  = lane & 15;
    const int kq   = lane >> 4;

    for (int i = t; i < 1536; i += 128) {
        const int r = i / 24, c = i - (i / 24) * 24;
        *(uint4*)&Wsh[r * 200 + c * 8] = *(const uint4*)&Wh[(size_t)(j0 + r) * 192 + c * 8];
        *(uint4*)&Wsl[r * 200 + c * 8] = *(const uint4*)&Wl[(size_t)(j0 + r) * 192 + c * 8];
    }

    const ushort* ah = Ahi + (size_t)(m0 + row) * 192 + kq * 8;
    const ushort* al = Alo + (size_t)(m0 + row) * 192 + kq * 8;

    f32x4 acc[4] = {f32x4{0,0,0,0}, f32x4{0,0,0,0}, f32x4{0,0,0,0}, f32x4{0,0,0,0}};

    __syncthreads();

#pragma unroll
    for (int ks = 0; ks < 6; ks++) {
        bf16x8 afh = *(const bf16x8*)(ah + ks * 32);
        bf16x8 afl = *(const bf16x8*)(al + ks * 32);
#pragma unroll
        for (int nt = 0; nt < 4; nt++) {
            const int widx = (nt * 16 + row) * 200 + kq * 8 + ks * 32;
            bf16x8 bh = *(const bf16x8*)&Wsh[widx];
            bf16x8 bl = *(const bf16x8*)&Wsl[widx];
            acc[nt] = __builtin_amdgcn_mfma_f32_16x16x32_bf16(afh, bh, acc[nt], 0, 0, 0);
            acc[nt] = __builtin_amdgcn_mfma_f32_16x16x32_bf16(afl, bh, acc[nt], 0, 0, 0);
            acc[nt] = __builtin_amdgcn_mfma_f32_16x16x32_bf16(afh, bl, acc[nt], 0, 0, 0);
        }
    }

#pragma unroll
    for (int nt = 0; nt < 4; nt++) {
        const int col = j0 + nt * 16 + row;
        const float bv = bias[col];
#pragma unroll
        for (int r = 0; r < 4; r++) {
            const int m = m0 + kq * 4 + r;
            C[(size_t)m * 192 + col] = acc[nt][r] + bv;
        }
    }
}

// ---------------------------------------------------------------------------
// Launch: cast_w -> gemm_qkv -> attn_mfma -> gemm_proj
// ---------------------------------------------------------------------------
extern "C" void kernel_launch(void* const* d_in, const int* in_sizes, int n_in,
                              void* d_out, int out_size, void* d_ws, size_t ws_size,
                              hipStream_t stream) {
    const float* x      = (const float*)d_in[0];
    const float* qkv_w  = (const float*)d_in[1];
    const float* qkv_b  = (const float*)d_in[2];
    const float* proj_w = (const float*)d_in[3];
    const float* proj_b = (const float*)d_in[4];
    // d_in[5] mask: fixed 7x11 window, recomputed analytically; unused.

    char* wsb = (char*)d_ws;
    float*  qkvws = (float*)(wsb + 0);          // [8192,576] f32 = 18.87 MB
    ushort* awshi = (ushort*)(wsb + 18874368);  // [8192,192] bf16 hi
    ushort* awslo = (ushort*)(wsb + 22020096);
    ushort* wqhi  = (ushort*)(wsb + 25165824);  // [576,192]
    ushort* wqlo  = (ushort*)(wsb + 25387008);
    ushort* wphi  = (ushort*)(wsb + 25608192);  // [192,192]
    ushort* wplo  = (ushort*)(wsb + 25681920);
    float*  out   = (float*)d_out;

    hipLaunchKernelGGL(cast_w, dim3(144), dim3(256), 0, stream,
                       qkv_w, proj_w, wqhi, wqlo, wphi, wplo);
    hipLaunchKernelGGL(gemm_qkv, dim3(128, 9), dim3(256), 0, stream,
                       x, wqhi, wqlo, qkv_b, qkvws);
    hipLaunchKernelGGL(attn_mfma, dim3(64, 8, 4), dim3(256), 0, stream,
                       qkvws, awshi, awslo);
    hipLaunchKernelGGL(gemm_proj, dim3(256, 3), dim3(128), 0, stream,
                       awshi, awslo, wphi, wplo, proj_b, out);
}